// Round 9
// baseline (156.302 us; speedup 1.0000x reference)
//
#include <hip/hip_runtime.h>
#include <hip/hip_bf16.h>

#define NHEAD 12
#define TSEQ 2048
#define CEMB 768
#define DHEAD 64
#define NBATCH 4

typedef __attribute__((ext_vector_type(8))) short bf16x8;
typedef __attribute__((ext_vector_type(4))) float f32x4;

__device__ __forceinline__ ushort f2bf(float f) {
  union { float f; unsigned u; } v; v.f = f;
  unsigned u = v.u;
  u += 0x7FFFu + ((u >> 16) & 1u);   // RNE to bf16
  return (ushort)(u >> 16);
}

// packed f32x2 -> bf16x2 (1 inst, RNE) — T12 primitive
__device__ __forceinline__ unsigned cvt_pk_bf16(float lo, float hi) {
  unsigned r;
  asm("v_cvt_pk_bf16_f32 %0, %1, %2" : "=v"(r) : "v"(lo), "v"(hi));
  return r;
}

// raw v_exp_f32: D = 2^S0 (scores are pre-scaled to log2 domain)
__device__ __forceinline__ float exp2_raw(float x) {
  float r;
  asm("v_exp_f32 %0, %1" : "=v"(r) : "v"(x));
  return r;
}

// wave-local LDS ordering (P buffer is wave-private; no block barrier needed)
__device__ __forceinline__ void lds_fence() {
  asm volatile("s_waitcnt lgkmcnt(0)" ::: "memory");
  __builtin_amdgcn_sched_barrier(0);   // rule 18: pin ops after the waitcnt
}

// ---------- fp32 -> bf16 bulk cast (x) ----------
__global__ __launch_bounds__(256)
void cast_x(const float* __restrict__ src, ushort* __restrict__ dst, int n) {
  int i = (blockIdx.x * 256 + threadIdx.x) * 8;
  if (i < n) {
    float4 v0 = *(const float4*)(src + i);
    float4 v1 = *(const float4*)(src + i + 4);
    bf16x8 w;
    w[0] = (short)f2bf(v0.x); w[1] = (short)f2bf(v0.y);
    w[2] = (short)f2bf(v0.z); w[3] = (short)f2bf(v0.w);
    w[4] = (short)f2bf(v1.x); w[5] = (short)f2bf(v1.y);
    w[6] = (short)f2bf(v1.z); w[7] = (short)f2bf(v1.w);
    *(bf16x8*)(dst + i) = w;
  }
}

// ---------- fp32 [R][C] -> bf16 [C][R] (weight pre-transpose) ----------
__global__ void transpose_w(const float* __restrict__ src, ushort* __restrict__ dst,
                            int R, int C) {
  __shared__ float tile[32][33];
  int c0 = blockIdx.x * 32, r0 = blockIdx.y * 32;
  int tx = threadIdx.x, ty = threadIdx.y;  // block (32,8)
#pragma unroll
  for (int j = 0; j < 4; ++j)
    tile[ty + j * 8][tx] = src[(size_t)(r0 + ty + j * 8) * C + c0 + tx];
  __syncthreads();
#pragma unroll
  for (int j = 0; j < 4; ++j)
    dst[(size_t)(c0 + ty + j * 8) * R + r0 + tx] = f2bf(tile[tx][ty + j * 8]);
}

// ---------- bf16 v [BH][T][D] -> vT [BH][D][T] ----------
__global__ void transpose_v(const ushort* __restrict__ src, ushort* __restrict__ dst) {
  __shared__ ushort tile[32][33];
  int bh = blockIdx.z;
  int t0 = blockIdx.x * 32, d0 = blockIdx.y * 32;
  int tx = threadIdx.x, ty = threadIdx.y;  // block (32,8)
  const ushort* s = src + (size_t)bh * TSEQ * DHEAD;
  ushort* o = dst + (size_t)bh * TSEQ * DHEAD;
#pragma unroll
  for (int j = 0; j < 4; ++j)
    tile[ty + j * 8][tx] = s[(t0 + ty + j * 8) * DHEAD + d0 + tx];
  __syncthreads();
#pragma unroll
  for (int j = 0; j < 4; ++j)
    o[(size_t)(d0 + ty + j * 8) * TSEQ + t0 + tx] = tile[tx][ty + j * 8];
}

// ---------- bf16 MFMA GEMM (m97 structure): C[M][N] = A(bf16,[M][K]) * BT(bf16,[N][K])^T + bias
// A and B tiles staged via global_load_lds width=16 (linear LDS dest), slot-XOR swizzle
// s ^= (row>>1)&3 pre-applied on the GLOBAL source + same XOR on the ds_read side (rule 21).
// EPI=0: fp32 out [M][N].  EPI=1: scatter qkv -> q/k/v bf16 [B,H,T,D],
//        q pre-scaled by 0.125*log2(e) (softmax runs in exp2 domain).
template<int EPI>
__global__ __launch_bounds__(256)
void gemm_bf16(const ushort* __restrict__ A, const ushort* __restrict__ BT,
               const float* __restrict__ bias, float* __restrict__ outF,
               ushort* __restrict__ qd, ushort* __restrict__ kd, ushort* __restrict__ vd,
               int M, int N, int K)
{
  __shared__ __align__(16) char smem[16384];   // As 8KB @0, Bs 8KB @8192
  const int t = threadIdx.x;
  const int lane = t & 63, wv = t >> 6;
  const int cc = lane & 15, gg = lane >> 4;
  const int m0 = blockIdx.y * 128, n0 = blockIdx.x * 128;
  const int wm = (wv >> 1) * 64, wn = (wv & 1) * 64;

  const int o0 = wv * 1024 + lane * 16;
  const int o1 = o0 + 4096;
  const int r0s = o0 >> 6, s0s = (o0 >> 4) & 3;
  const int r1s = o1 >> 6, s1s = (o1 >> 4) & 3;
  const size_t Kb = (size_t)K * 2;
  const char* a0p = (const char*)A  + (size_t)(m0 + r0s) * Kb + ((s0s ^ ((r0s >> 1) & 3)) << 4);
  const char* a1p = (const char*)A  + (size_t)(m0 + r1s) * Kb + ((s1s ^ ((r1s >> 1) & 3)) << 4);
  const char* b0p = (const char*)BT + (size_t)(n0 + r0s) * Kb + ((s0s ^ ((r0s >> 1) & 3)) << 4);
  const char* b1p = (const char*)BT + (size_t)(n0 + r1s) * Kb + ((s1s ^ ((r1s >> 1) & 3)) << 4);

  char* As = smem;
  char* Bs = smem + 8192;

  f32x4 acc[4][4];
#pragma unroll
  for (int i = 0; i < 4; ++i)
#pragma unroll
    for (int j = 0; j < 4; ++j) acc[i][j] = (f32x4){0.f, 0.f, 0.f, 0.f};

  const int KB = K * 2;   // row bytes
  for (int kb = 0; kb < KB; kb += 64) {
    __builtin_amdgcn_global_load_lds(
        (const __attribute__((address_space(1))) unsigned*)(a0p + kb),
        (__attribute__((address_space(3))) unsigned*)(As + wv * 1024), 16, 0, 0);
    __builtin_amdgcn_global_load_lds(
        (const __attribute__((address_space(1))) unsigned*)(a1p + kb),
        (__attribute__((address_space(3))) unsigned*)(As + wv * 1024 + 4096), 16, 0, 0);
    __builtin_amdgcn_global_load_lds(
        (const __attribute__((address_space(1))) unsigned*)(b0p + kb),
        (__attribute__((address_space(3))) unsigned*)(Bs + wv * 1024), 16, 0, 0);
    __builtin_amdgcn_global_load_lds(
        (const __attribute__((address_space(1))) unsigned*)(b1p + kb),
        (__attribute__((address_space(3))) unsigned*)(Bs + wv * 1024 + 4096), 16, 0, 0);
    __syncthreads();   // drains vmcnt(0): staged tile visible to all waves
    bf16x8 fa[4], fb[4];
#pragma unroll
    for (int i = 0; i < 4; ++i) {
      const int r = wm + i * 16 + cc;
      fa[i] = *(const bf16x8*)(As + r * 64 + ((gg ^ ((r >> 1) & 3)) << 4));
    }
#pragma unroll
    for (int j = 0; j < 4; ++j) {
      const int r = wn + j * 16 + cc;
      fb[j] = *(const bf16x8*)(Bs + r * 64 + ((gg ^ ((r >> 1) & 3)) << 4));
    }
    __builtin_amdgcn_s_setprio(1);
#pragma unroll
    for (int i = 0; i < 4; ++i)
#pragma unroll
      for (int j = 0; j < 4; ++j)
        acc[i][j] = __builtin_amdgcn_mfma_f32_16x16x32_bf16(fa[i], fb[j], acc[i][j], 0, 0, 0);
    __builtin_amdgcn_s_setprio(0);
    __syncthreads();   // all reads done before next stage overwrites
  }

#pragma unroll
  for (int i = 0; i < 4; ++i) {
#pragma unroll
    for (int j = 0; j < 4; ++j) {
      int gm0 = m0 + wm + i * 16 + gg * 4;
      int gn  = n0 + wn + j * 16 + cc;
      float bv = bias[gn];
      if (EPI == 0) {
#pragma unroll
        for (int e = 0; e < 4; ++e)
          outF[(size_t)(gm0 + e) * N + gn] = acc[i][j][e] + bv;
      } else {
        int which = gn / CEMB;
        int r = gn - which * CEMB;
        int hh = r >> 6, dd = r & 63;
        ushort* dst = which == 0 ? qd : (which == 1 ? kd : vd);
        // q scale: 1/sqrt(D) * log2(e) — softmax computed with exp2
        float sc = (which == 0) ? 0.125f * 1.4426950408889634f : 1.0f;
#pragma unroll
        for (int e = 0; e < 4; ++e) {
          int gm = gm0 + e;
          int tt = gm & (TSEQ - 1), bb = gm >> 11;
          dst[(size_t)((bb * NHEAD + hh) * TSEQ + tt) * DHEAD + dd] = f2bf((acc[i][j][e] + bv) * sc);
        }
      }
    }
  }
}

// ---------- flash attention: QBLK=32/wave, paired 128-row supertiles ----------
// LDS-read-BW-bound fix: each wave serves 32 q-rows (2 per lane: cc, cc+16) so the
// shared 64x64 K/V LDS tiles are read once per 32 q instead of per 16 (DS bytes/q halves).
// Block = 4 waves x 32 q = 128-row supertile; pass pair (sb, 15-sb) -> exactly 34
// key-tile iterations per block (balanced under any dispatch->CU mapping).
// Grid 384 = 8 XCD-slots x 8 pairs x 6; same-bh blocks share an XCD slot (T1).
// K/V via global_load_lds, rule-21 pre-swizzled source, XOR (row&7)<<4.
// Softmax in exp2 domain; defer-max THR = 8*log2e. A wave's diagonal tile == its
// last active tile (32-row chunks are 64-aligned); waves 0-1 idle (barriers only)
// on the block's final iteration.
__global__ __launch_bounds__(256)
void attn_fwd(const ushort* __restrict__ qg, const ushort* __restrict__ kg,
              const ushort* __restrict__ vTg, ushort* __restrict__ ybb)
{
  // LDS: K[2] @ 0 (2 x 8KB, swizzled), V[2] @ 16384, P @ 32768 (4 waves x 2 qh x 2KB)
  __shared__ __align__(16) char smem[49152];
  const int t = threadIdx.x, lane = t & 63, w = t >> 6;
  const int cc = lane & 15, gg = lane >> 4;
  const int L = blockIdx.x;
  const int li = L >> 3;
  const int pp = li & 7;                       // pair index 0..7
  const int bh = (L & 7) + 8 * (li >> 3);      // same bh -> same XCD slot
  const int b = bh / NHEAD, h = bh - b * NHEAD;

  const char* Kg = (const char*)(kg + (size_t)bh * TSEQ * DHEAD);   // [T][64], 128B rows
  const char* Vg = (const char*)(vTg + (size_t)bh * TSEQ * DHEAD);  // [64][T], 4096B rows

  const int srow = lane >> 3;                        // row&7 within 8-row chunk
  const int ssw  = ((lane & 7) * 16) ^ (srow << 4);  // pre-swizzled source colbyte

  ushort* Pw = (ushort*)(smem + 32768 + w * 4096);   // [qh][16][64] ushort, swizzled
  const int sw8 = (cc & 7) << 3;

  auto stage = [&](int ppb, int kt) {
#pragma unroll
    for (int i = 0; i < 2; ++i) {
      const int c = w * 2 + i;
      const char* gk = Kg + (size_t)(kt * 64 + c * 8 + srow) * 128 + ssw;
      __builtin_amdgcn_global_load_lds(
          (const __attribute__((address_space(1))) unsigned*)gk,
          (__attribute__((address_space(3))) unsigned*)(smem + ppb * 8192 + c * 1024),
          16, 0, 0);
      const char* gv = Vg + (size_t)(c * 8 + srow) * (TSEQ * 2) + (size_t)kt * 128 + ssw;
      __builtin_amdgcn_global_load_lds(
          (const __attribute__((address_space(1))) unsigned*)gv,
          (__attribute__((address_space(3))) unsigned*)(smem + 16384 + ppb * 8192 + c * 1024),
          16, 0, 0);
    }
  };

  int p = 0;
  for (int pass = 0; pass < 2; ++pass) {
    const int sb = pass ? (15 - pp) : pp;
    const int qrow0 = sb * 128 + w * 32;        // wave's 32 q-rows
    const int ktmax_w = qrow0 >> 6;             // last active (== diagonal) tile
    const int ktmax_b = 2 * sb + 1;             // block bound
    const int qloc = qrow0 & 63;                // 0 or 32

    const ushort* Qp = qg + ((size_t)bh * TSEQ + qrow0) * DHEAD;
    bf16x8 fq[2][2];
#pragma unroll
    for (int qh = 0; qh < 2; ++qh)
#pragma unroll
      for (int hf = 0; hf < 2; ++hf)
        fq[qh][hf] = *(const bf16x8*)(Qp + (16 * qh + cc) * DHEAD + hf * 32 + 8 * gg);

    f32x4 o[4][2];   // o[dt][qh][e] = O^T[d=16dt+4gg+e][q = qrow0+16qh+cc]
#pragma unroll
    for (int i = 0; i < 4; ++i)
#pragma unroll
      for (int qh = 0; qh < 2; ++qh) o[i][qh] = (f32x4){0.f, 0.f, 0.f, 0.f};
    float m[2] = {-1e30f, -1e30f}, l[2] = {0.f, 0.f};

    stage(p, 0);
    asm volatile("s_waitcnt vmcnt(0)" ::: "memory");
    __syncthreads();

    for (int kt = 0; kt <= ktmax_b; ++kt) {
      if (kt < ktmax_b) stage(p ^ 1, kt + 1);   // prefetch next tile

      if (kt <= ktmax_w) {
        const char* Kl = smem + p * 8192;
        const char* Vl = smem + 16384 + p * 8192;
        f32x4 st[4][2];   // st[ct][qh][e] = S^T[key=16ct+4gg+e][q]
#pragma unroll
        for (int ct = 0; ct < 4; ++ct)
#pragma unroll
          for (int qh = 0; qh < 2; ++qh) st[ct][qh] = (f32x4){0.f, 0.f, 0.f, 0.f};
        __builtin_amdgcn_s_setprio(1);
#pragma unroll
        for (int ct = 0; ct < 4; ++ct) {
          const int r = ct * 16 + cc;
          const char* kb = Kl + r * 128;
          bf16x8 fk0 = *(const bf16x8*)(kb + ((gg * 16) ^ ((r & 7) << 4)));
          bf16x8 fk1 = *(const bf16x8*)(kb + ((64 + gg * 16) ^ ((r & 7) << 4)));
#pragma unroll
          for (int qh = 0; qh < 2; ++qh) {
            st[ct][qh] = __builtin_amdgcn_mfma_f32_16x16x32_bf16(fk0, fq[qh][0], st[ct][qh], 0, 0, 0);
            st[ct][qh] = __builtin_amdgcn_mfma_f32_16x16x32_bf16(fk1, fq[qh][1], st[ct][qh], 0, 0, 0);
          }
        }
        __builtin_amdgcn_s_setprio(0);

        if (kt == ktmax_w) {   // causal mask on the diagonal tile
#pragma unroll
          for (int ct = 0; ct < 4; ++ct)
#pragma unroll
            for (int qh = 0; qh < 2; ++qh)
#pragma unroll
              for (int e = 0; e < 4; ++e)
                if (ct * 16 + gg * 4 + e > qloc + 16 * qh + cc) st[ct][qh][e] = -1e30f;
        }
#pragma unroll
        for (int qh = 0; qh < 2; ++qh) {
          float ml = st[0][qh][0];
#pragma unroll
          for (int ct = 0; ct < 4; ++ct)
#pragma unroll
            for (int e = 0; e < 4; ++e) ml = fmaxf(ml, st[ct][qh][e]);
          ml = fmaxf(ml, __shfl_xor(ml, 16, 64));
          ml = fmaxf(ml, __shfl_xor(ml, 32, 64));
          float mn = m[qh];
          if (!__all(ml - m[qh] <= 11.54f)) {   // defer-max (T13), THR = 8*log2e
            mn = fmaxf(m[qh], ml);
            float al = exp2_raw(m[qh] - mn);
#pragma unroll
            for (int dt = 0; dt < 4; ++dt)
#pragma unroll
              for (int e = 0; e < 4; ++e) o[dt][qh][e] *= al;
            l[qh] *= al;
            m[qh] = mn;
          }
          float ps = 0.f;
#pragma unroll
          for (int ct = 0; ct < 4; ++ct)
#pragma unroll
            for (int e = 0; e < 4; ++e) {
              float pv = exp2_raw(st[ct][qh][e] - mn);
              st[ct][qh][e] = pv; ps += pv;
            }
#pragma unroll
          for (int ct = 0; ct < 4; ++ct) {
            uint2 pw;
            pw.x = cvt_pk_bf16(st[ct][qh][0], st[ct][qh][1]);
            pw.y = cvt_pk_bf16(st[ct][qh][2], st[ct][qh][3]);
            *(uint2*)&Pw[qh * 1024 + cc * 64 + ((ct * 16 + gg * 4) ^ sw8)] = pw;
          }
          ps += __shfl_xor(ps, 16, 64);
          ps += __shfl_xor(ps, 32, 64);
          l[qh] += ps;
        }
        lds_fence();   // wave-local: P writes complete before fragment reads
        __builtin_amdgcn_s_setprio(1);
#pragma unroll
        for (int kc = 0; kc < 2; ++kc) {
          bf16x8 pb0 = *(const bf16x8*)&Pw[cc * 64 + ((kc * 32 + 8 * gg) ^ sw8)];
          bf16x8 pb1 = *(const bf16x8*)&Pw[1024 + cc * 64 + ((kc * 32 + 8 * gg) ^ sw8)];
#pragma unroll
          for (int dt = 0; dt < 4; ++dt) {
            const int rd = dt * 16 + cc;
            bf16x8 fv = *(const bf16x8*)(Vl + rd * 128 + ((kc * 64 + gg * 16) ^ ((rd & 7) << 4)));
            o[dt][0] = __builtin_amdgcn_mfma_f32_16x16x32_bf16(fv, pb0, o[dt][0], 0, 0, 0);
            o[dt][1] = __builtin_amdgcn_mfma_f32_16x16x32_bf16(fv, pb1, o[dt][1], 0, 0, 0);
          }
        }
        __builtin_amdgcn_s_setprio(0);
      }
      asm volatile("s_waitcnt vmcnt(0)" ::: "memory");   // next tile's stage landed
      __syncthreads();                                   // all waves done with buf p
      p ^= 1;
    }

#pragma unroll
    for (int qh = 0; qh < 2; ++qh) {
      float inv = 1.0f / l[qh];
      ushort* yrow = ybb + (size_t)(b * TSEQ + qrow0 + 16 * qh + cc) * CEMB + h * DHEAD;
#pragma unroll
      for (int dt = 0; dt < 4; ++dt) {
        uint2 pw;
        pw.x = cvt_pk_bf16(o[dt][qh][0] * inv, o[dt][qh][1] * inv);
        pw.y = cvt_pk_bf16(o[dt][qh][2] * inv, o[dt][qh][3] * inv);
        *(uint2*)(yrow + dt * 16 + gg * 4) = pw;
      }
    }
  }
}

extern "C" void kernel_launch(void* const* d_in, const int* in_sizes, int n_in,
                              void* d_out, int out_size, void* d_ws, size_t ws_size,
                              hipStream_t stream)
{
  (void)in_sizes; (void)n_in; (void)out_size; (void)ws_size;
  const float* x  = (const float*)d_in[0];
  const float* Wa = (const float*)d_in[1];
  const float* ba = (const float*)d_in[2];
  const float* Wo = (const float*)d_in[3];
  const float* bo = (const float*)d_in[4];
  float* out = (float*)d_out;

  char* p = (char*)d_ws;
  ushort* WaT  = (ushort*)p; p += (size_t)3 * CEMB * CEMB * 2;               // [2304][768] bf16
  ushort* WoT  = (ushort*)p; p += (size_t)CEMB * CEMB * 2;                   // [768][768] bf16
  ushort* xb   = (ushort*)p; p += (size_t)NBATCH * TSEQ * CEMB * 2;          // x bf16 [B*T][C]
  ushort* qb   = (ushort*)p; p += (size_t)NBATCH * NHEAD * TSEQ * DHEAD * 2; // [B,H,T,D]
  ushort* kb   = (ushort*)p; p += (size_t)NBATCH * NHEAD * TSEQ * DHEAD * 2;
  ushort* vtmp = (ushort*)p; p += (size_t)NBATCH * NHEAD * TSEQ * DHEAD * 2;
  ushort* vT   = (ushort*)p; p += (size_t)NBATCH * NHEAD * TSEQ * DHEAD * 2; // [B,H,D,T]
  ushort* yb   = (ushort*)p; p += (size_t)NBATCH * TSEQ * CEMB * 2;          // attn out bf16 [B*T][C]

  dim3 tb(32, 8);
  cast_x<<<NBATCH * TSEQ * CEMB / (256 * 8), 256, 0, stream>>>(x, xb, NBATCH * TSEQ * CEMB);
  transpose_w<<<dim3(3 * CEMB / 32, CEMB / 32), tb, 0, stream>>>(Wa, WaT, CEMB, 3 * CEMB);
  transpose_w<<<dim3(CEMB / 32, CEMB / 32), tb, 0, stream>>>(Wo, WoT, CEMB, CEMB);
  gemm_bf16<1><<<dim3(3 * CEMB / 128, NBATCH * TSEQ / 128), 256, 0, stream>>>(
      xb, WaT, ba, nullptr, qb, kb, vtmp, NBATCH * TSEQ, 3 * CEMB, CEMB);
  transpose_v<<<dim3(TSEQ / 32, DHEAD / 32, NBATCH * NHEAD), tb, 0, stream>>>(vtmp, vT);
  attn_fwd<<<dim3(8 * 8 * 6), 256, 0, stream>>>(qb, kb, vT, yb);
  gemm_bf16<0><<<dim3(CEMB / 128, NBATCH * TSEQ / 128), 256, 0, stream>>>(
      yb, WoT, bo, out, nullptr, nullptr, nullptr, NBATCH * TSEQ, CEMB, CEMB);
}